// Round 17
// baseline (313.801 us; speedup 1.0000x reference)
//
#include <hip/hip_runtime.h>
#include <cstdint>
#include <cstddef>

typedef __attribute__((ext_vector_type(16))) float f32x16;
typedef __attribute__((ext_vector_type(8))) short short8;

// ---------- bf16 helpers (bit-level, header-version independent) ----------
__device__ __forceinline__ unsigned short f2bf(float f) {
  unsigned int u = __float_as_uint(f);
  u += 0x7fffu + ((u >> 16) & 1u);            // round to nearest even
  return (unsigned short)(u >> 16);
}
__device__ __forceinline__ float bf2f(unsigned short h) {
  return __uint_as_float(((unsigned int)h) << 16);
}
__device__ __forceinline__ float bflo(unsigned int w) {   // low bf16 of a word
  return __uint_as_float(w << 16);
}
__device__ __forceinline__ float bfhi(unsigned int w) {   // high bf16 of a word
  return __uint_as_float(w & 0xffff0000u);
}

__device__ __forceinline__ void gload16(const unsigned short* g, unsigned short* l) {
  __builtin_amdgcn_global_load_lds(
      (const __attribute__((address_space(1))) void*)g,
      (__attribute__((address_space(3))) void*)l, 16, 0, 0);
}

// ---------- merged pre-pass: cast x, transpose+interleave wf, transpose wd,
// pack biases. One launch, block-range dispatch. ----------
// wfh row layout: phi(j) = j<2048 ? 2j : 2(j-2048)+1  ->  proj col 2e = k_e,
// col 2e+1 = hx_e: scans read ONE coalesced u32 per step.
__global__ __launch_bounds__(256) void k_prep(const float* __restrict__ x,
                                              unsigned short* __restrict__ xhi,
                                              const float* __restrict__ wf,
                                              unsigned short* __restrict__ wfh,
                                              const float* __restrict__ wd,
                                              unsigned short* __restrict__ wdt,
                                              const float* __restrict__ bfv,
                                              float2* __restrict__ bfi) {
  int blk = blockIdx.x;
  if (blk < 16384) {                       // cast x f32 -> bf16
    size_t i = ((size_t)blk * 256 + threadIdx.x) * 4;
    float4 v = *(const float4*)(x + i);
    *(ushort4*)(xhi + i) = make_ushort4(f2bf(v.x), f2bf(v.y), f2bf(v.z), f2bf(v.w));
    return;
  }
  blk -= 16384;
  if (blk < 4096) {                        // wf [1024][4096] -> wfh interleaved [4096][1024]
    __shared__ float tile[32][33];
    int tx = threadIdx.x & 31, ty = threadIdx.x >> 5;
    int bx = blk & 127, by = blk >> 7;     // 128 x 32
    int c0 = bx * 32, r0 = by * 32;
#pragma unroll
    for (int i = 0; i < 4; ++i)
      tile[ty + 8 * i][tx] = wf[(size_t)(r0 + ty + 8 * i) * 4096 + (c0 + tx)];
    __syncthreads();
#pragma unroll
    for (int i = 0; i < 4; ++i) {
      int j = c0 + ty + 8 * i;             // original wf column
      int r = (j < 2048) ? (2 * j) : (2 * (j - 2048) + 1);
      wfh[(size_t)r * 1024 + (r0 + tx)] = f2bf(tile[tx][ty + 8 * i]);
    }
    return;
  }
  blk -= 4096;
  if (blk < 2048) {                        // wd [2048][1024] -> wdt [1024][2048]
    __shared__ float tile[32][33];
    int tx = threadIdx.x & 31, ty = threadIdx.x >> 5;
    int bx = blk & 31, by = blk >> 5;      // 32 x 64
    int c0 = bx * 32, r0 = by * 32;
#pragma unroll
    for (int i = 0; i < 4; ++i)
      tile[ty + 8 * i][tx] = wd[(size_t)(r0 + ty + 8 * i) * 1024 + (c0 + tx)];
    __syncthreads();
#pragma unroll
    for (int i = 0; i < 4; ++i)
      wdt[(size_t)(c0 + ty + 8 * i) * 2048 + (r0 + tx)] = f2bf(tile[tx][ty + 8 * i]);
    return;
  }
  blk -= 2048;                             // bias pack: bfi[e] = (b_f[e], b_f[2048+e])
  int i = blk * 256 + threadIdx.x;
  if (i < 2048) bfi[i] = make_float2(bfv[i], bfv[2048 + i]);
}

// ---------- GEMM: A[M][K] (bf16, k-contig), B[N][K] (bf16, k-contig) -> C[M][N]
// R17: R16's frame (256x256 tile, BK=64, ring-2 128KB, distance-1 prefetch,
// one exact vmcnt(0) + one barrier per K-64) with the MFMA shape switched
// 16x16x32 -> 32x32x16. Rationale: shape has 15% higher measured pipe ceiling
// (2382 vs 2075 TF µbench; per-K-tile MFMA floor 2483 -> 2066 cyc/CU), halves
// MFMA instruction count, and doubles C-write run length (64B contiguous).
// Wave-tile 128x64 = 4 m-blocks x 2 n-blocks of 32.
// Fragment convention (pi-invariance, same trick as 16x16 since R1): lane l
// supplies element j of k-chunk g = (l>>5)*8-group: A[row=l&31][k=2ks+(l>>5)],
// B[col=l&31][k=2ks+(l>>5)] — identical lane->k map on both operands, so the
// contraction is correct regardless of HW k-labeling. C/D layout HW-verified:
// col = lane&31, row = (reg&3) + 8*(reg>>2) + 4*(lane>>5), reg in [0,16).
// LDS swizzle: same 8-slot family as R16 (phys slot p at row r holds global
// chunk p ^ ((r>>1)&7); stage linear-dest with pre-swizzled global chunk).
// Frag reads are 4-way banked (32 rows over 8 slots — pigeonhole minimum);
// m136: 4-way = 1.58x on the ~290cyc read term, negligible.
// Sync/race proofs unchanged from R16 (exact vmcnt(0) certification;
// stage(u+1) after barrier(u); reads of buf (u-1) complete pre-barrier).
template<bool BF16OUT>
__global__ __launch_bounds__(512, 2) void k_gemm(const unsigned short* __restrict__ A,
                                                 const unsigned short* __restrict__ B,
                                                 void* __restrict__ Cv, int M, int N, int K) {
  __shared__ unsigned short lds[65536];      // 2 bufs x 32768 shorts = 128 KB
  const int tid = threadIdx.x, wave = tid >> 6, lane = tid & 63;
  const size_t row0 = (size_t)blockIdx.x * 256;
  const size_t col0 = (size_t)blockIdx.y * 256;
  const int wr = wave >> 2, wc = wave & 3;   // 2M x 4N waves, wave-tile 128x64
  const int r32 = lane & 31;                 // MFMA row/col index
  const int hi = lane >> 5;                  // k-chunk half 0/1
  const int xm = (r32 >> 1) & 7;             // row swizzle mask
  const int gchunk = (tid & 7) ^ ((tid >> 4) & 7);   // stage pre-swizzled k-chunk

  f32x16 acc[4][2];
#pragma unroll
  for (int i = 0; i < 4; ++i)
#pragma unroll
    for (int j = 0; j < 2; ++j)
#pragma unroll
      for (int r = 0; r < 16; ++r) acc[i][j][r] = 0.f;

  // stage one 8KB region (arr 0=A,1=B; reg = 64-row slab 0..3) of K-tile kt
  // into ring buffer b. Thread: row reg*64 + (tid>>3), 16B at slot tid&7.
  auto SREG = [&](int b, int arr, int reg, int kt) {
    const unsigned short* src = arr ? B : A;
    size_t grow = (arr ? col0 : row0) + (size_t)(reg * 64 + (tid >> 3));
    gload16(src + grow * (size_t)K + (size_t)(kt * 64 + gchunk * 8),
            &lds[(b << 15) + arr * 16384 + reg * 4096 + wave * 512]);
  };
  auto STAGE = [&](int b, int kt) {
#pragma unroll
    for (int reg = 0; reg < 4; ++reg) SREG(b, 0, reg, kt);
#pragma unroll
    for (int reg = 0; reg < 4; ++reg) SREG(b, 1, reg, kt);
  };

  // fragment offsets (shorts): row*64 + swizzled-slot*8; k-chunk = 2*ks + hi
  auto AOFF = [&](int mb, int ks) -> int {
    int r = wr * 128 + mb * 32 + r32;
    return r * 64 + (((ks * 2 + hi) ^ xm) * 8);
  };
  auto BOFF = [&](int nb, int ks) -> int {
    int c = wc * 64 + nb * 32 + r32;
    return 16384 + c * 64 + (((ks * 2 + hi) ^ xm) * 8);
  };

  STAGE(0, 0);                               // prologue
  const int nT = K >> 6;
  for (int u = 0; u < nT; ++u) {
    const unsigned short* buf = &lds[(u & 1) << 15];
    asm volatile("s_waitcnt vmcnt(0)" ::: "memory");   // exact cert of tile u
    asm volatile("s_barrier" ::: "memory");
    if (u + 1 < nT) STAGE((u & 1) ^ 1, u + 1);         // distance-1 prefetch
    short8 b8[4][2];                                    // [ks][nb]
#pragma unroll
    for (int ks = 0; ks < 4; ++ks)
#pragma unroll
      for (int nb = 0; nb < 2; ++nb)
        b8[ks][nb] = *(const short8*)&buf[BOFF(nb, ks)];
#pragma unroll
    for (int ks = 0; ks < 4; ++ks) {
      short8 a4[4];
#pragma unroll
      for (int mb = 0; mb < 4; ++mb)
        a4[mb] = *(const short8*)&buf[AOFF(mb, ks)];
      __builtin_amdgcn_s_setprio(1);
#pragma unroll
      for (int mb = 0; mb < 4; ++mb)
#pragma unroll
        for (int nb = 0; nb < 2; ++nb)
          acc[mb][nb] = __builtin_amdgcn_mfma_f32_32x32x16_bf16(a4[mb], b8[ks][nb], acc[mb][nb], 0, 0, 0);
      __builtin_amdgcn_s_setprio(0);
    }
  }

  // C/D layout (HW-verified, m74/m101): col = lane&31,
  // row = (reg&3) + 8*(reg>>2) + 4*(lane>>5)
#pragma unroll
  for (int mb = 0; mb < 4; ++mb)
#pragma unroll
    for (int nb = 0; nb < 2; ++nb) {
      size_t col = col0 + wc * 64 + nb * 32 + r32;
#pragma unroll
      for (int reg = 0; reg < 16; ++reg) {
        size_t row = row0 + wr * 128 + mb * 32 + (reg & 3) + 8 * (reg >> 2) + 4 * hi;
        if (BF16OUT) {
          ((unsigned short*)Cv)[row * (size_t)N + col] = f2bf(acc[mb][nb][reg]);
        } else {
          ((float*)Cv)[row * (size_t)N + col] = acc[mb][nb][reg];
        }
      }
    }
}

// ---------- scan constants ----------
#define SB 4
#define ST 4096
#define SE 2048
#define CHUNK 64
#define NCHUNK 64
#define NCHAIN (SB * SE)  // 8192

// LINEAR-SPACE scan: h_t = c*h_{t-1} + v, c = sigmoid(-k), v = sigmoid(k)*g(hx).
// All positive, h in [~1e-7, ~150] — f32-safe. Cancellation-free c.
// proj INTERLEAVED: word e of a row = (k_e lo, hx_e hi).
__device__ __forceinline__ void transform_lin(float k, float hx, float& c, float& v) {
  float e = __expf(-k);
  float r = __builtin_amdgcn_rcpf(1.f + e);    // sigmoid(k)
  c = e * r;                                   // sigmoid(-k), no cancellation
  float e2 = __expf(-hx);
  float sg = __builtin_amdgcn_rcpf(1.f + e2);  // sigmoid(hx)
  float g = (hx >= 0.f) ? (hx + 0.5f) : sg;    // g(hx)
  v = r * g;
}

// K2: transforms + chunk-local linear scan (from 0) -> chunk summaries
__global__ __launch_bounds__(256) void k_scan1(const unsigned int* __restrict__ proj32,
                                               const float2* __restrict__ bfi,
                                               float* __restrict__ Ac,
                                               float* __restrict__ Bc) {
  int idx = blockIdx.x * 256 + threadIdx.x;  // (c, b, e) with e fastest
  int e = idx & (SE - 1), b = (idx >> 11) & 3, c = idx >> 13;
  const float2 bb = bfi[e];
  float A = 1.f, S = 0.f;
  size_t base = ((size_t)(b * ST + c * CHUNK)) * SE + e;
  for (int i = 0; i < CHUNK; ++i) {
    unsigned int w = proj32[base];
    float cc, vv;
    transform_lin(bflo(w) + bb.x, bfhi(w) + bb.y, cc, vv);
    A *= cc;
    S = fmaf(cc, S, vv);
    base += SE;
  }
  int chain = b * SE + e;
  Ac[(size_t)c * NCHAIN + chain] = A;
  Bc[(size_t)c * NCHAIN + chain] = S;
}

// K3: scan over chunk summaries: H_{c+1} = A_c*H_c + B_c; H_0 = exp(lh0)
__global__ __launch_bounds__(256) void k_scan2(const float* __restrict__ lh0,
                                               const float* __restrict__ Ac,
                                               const float* __restrict__ Bc,
                                               float* __restrict__ Hin) {
  int chain = blockIdx.x * 256 + threadIdx.x;  // 8192 = b*E + e
  float H = __expf(lh0[chain]);
  for (int c = 0; c < NCHUNK; ++c) {
    Hin[(size_t)c * NCHAIN + chain] = H;
    H = fmaf(Ac[(size_t)c * NCHAIN + chain], H, Bc[(size_t)c * NCHAIN + chain]);
  }
}

// K4: replay linear scan; emit h_t (bf16) and out2 = log(h) slices
__global__ __launch_bounds__(256) void k_scan3(const unsigned int* __restrict__ proj32,
                                               const float2* __restrict__ bfi,
                                               const float* __restrict__ Hin,
                                               unsigned short* __restrict__ ht,
                                               float* __restrict__ out2) {
  int idx = blockIdx.x * 256 + threadIdx.x;
  int e = idx & (SE - 1), b = (idx >> 11) & 3, c = idx >> 13;
  const float2 bb = bfi[e];
  float S = Hin[(size_t)c * NCHAIN + b * SE + e];
  size_t base = ((size_t)(b * ST + c * CHUNK)) * SE + e;
  int t = c * CHUNK;
  size_t hto = ((size_t)(b * ST + t)) * SE + e;
  for (int i = 0; i < CHUNK; ++i, ++t) {
    unsigned int w = proj32[base];
    float cc, vv;
    transform_lin(bflo(w) + bb.x, bfhi(w) + bb.y, cc, vv);
    S = fmaf(cc, S, vv);
    ht[hto] = f2bf(S);
    if (t >= 2 && ((t - 2) % 3) == 0) {   // t in {2,5,...,4094}
      int j = (t - 2) / 3;
      out2[((size_t)b * 1365 + j) * SE + e] = __logf(S);
    }
    base += SE;
    hto += SE;
  }
}

// ---------- launch ----------
extern "C" void kernel_launch(void* const* d_in, const int* in_sizes, int n_in,
                              void* d_out, int out_size, void* d_ws, size_t ws_size,
                              hipStream_t stream) {
  const float* x   = (const float*)d_in[0];
  const float* lh0 = (const float*)d_in[1];
  const float* wf  = (const float*)d_in[2];
  const float* bfv = (const float*)d_in[3];
  const float* wd  = (const float*)d_in[4];
  float* out1 = (float*)d_out;
  float* out2 = out1 + (size_t)SB * ST * 1024;

  char* p = (char*)d_ws;
  unsigned short* proj = (unsigned short*)p; p += 16384ull * 4096 * 2;  // 134 MB bf16
  unsigned short* xhi  = (unsigned short*)p; p += 16384ull * 1024 * 2;
  unsigned short* wfh  = (unsigned short*)p; p += 4096ull * 1024 * 2;
  unsigned short* wdt  = (unsigned short*)p; p += 1024ull * 2048 * 2;
  unsigned short* ht   = (unsigned short*)p; p += 16384ull * 2048 * 2;  // 67 MB
  float* Ac            = (float*)p;          p += 64ull * 8192 * 4;
  float* Bc            = (float*)p;          p += 64ull * 8192 * 4;
  float* Hin           = (float*)p;          p += 64ull * 8192 * 4;
  float2* bfi          = (float2*)p;         p += 2048ull * 8;

  // merged pre-pass
  hipLaunchKernelGGL(k_prep, dim3(16384 + 4096 + 2048 + 8), dim3(256), 0, stream,
                     x, xhi, wf, wfh, wd, wdt, bfv, bfi);
  // GEMM1 (bf16 in/out): proj = x @ w_f (cols interleaved via wfh row perm)
  hipLaunchKernelGGL((k_gemm<true>), dim3(64, 16), dim3(512), 0, stream,
                     xhi, wfh, (void*)proj, 16384, 4096, 1024);
  // 3-pass chunked LINEAR-space scan (proj read-only, word-coalesced)
  hipLaunchKernelGGL(k_scan1, dim3(2048), dim3(256), 0, stream,
                     (const unsigned int*)proj, bfi, Ac, Bc);
  hipLaunchKernelGGL(k_scan2, dim3(32), dim3(256), 0, stream, lh0, Ac, Bc, Hin);
  hipLaunchKernelGGL(k_scan3, dim3(2048), dim3(256), 0, stream,
                     (const unsigned int*)proj, bfi, Hin, ht, out2);
  // GEMM2 (bf16 in, f32 out): out1 = h_t @ w_down
  hipLaunchKernelGGL((k_gemm<false>), dim3(64, 4), dim3(512), 0, stream,
                     ht, wdt, (void*)out1, 16384, 1024, 2048);
}

// Round 18
// 299.468 us; speedup vs baseline: 1.0479x; 1.0479x over previous
//
#include <hip/hip_runtime.h>
#include <cstdint>
#include <cstddef>

typedef __attribute__((ext_vector_type(4))) float f32x4;
typedef __attribute__((ext_vector_type(8))) short short8;

// ---------- bf16 helpers (bit-level, header-version independent) ----------
__device__ __forceinline__ unsigned short f2bf(float f) {
  unsigned int u = __float_as_uint(f);
  u += 0x7fffu + ((u >> 16) & 1u);            // round to nearest even
  return (unsigned short)(u >> 16);
}
__device__ __forceinline__ float bf2f(unsigned short h) {
  return __uint_as_float(((unsigned int)h) << 16);
}
__device__ __forceinline__ float bflo(unsigned int w) {   // low bf16 of a word
  return __uint_as_float(w << 16);
}
__device__ __forceinline__ float bfhi(unsigned int w) {   // high bf16 of a word
  return __uint_as_float(w & 0xffff0000u);
}

__device__ __forceinline__ void gload16(const unsigned short* g, unsigned short* l) {
  __builtin_amdgcn_global_load_lds(
      (const __attribute__((address_space(1))) void*)g,
      (__attribute__((address_space(3))) void*)l, 16, 0, 0);
}

// ---------- merged pre-pass: cast x, transpose+interleave wf, transpose wd,
// pack biases. One launch, block-range dispatch. ----------
// wfh row layout: phi(j) = j<2048 ? 2j : 2(j-2048)+1  ->  proj col 2e = k_e,
// col 2e+1 = hx_e: scans read ONE coalesced u32 per step.
__global__ __launch_bounds__(256) void k_prep(const float* __restrict__ x,
                                              unsigned short* __restrict__ xhi,
                                              const float* __restrict__ wf,
                                              unsigned short* __restrict__ wfh,
                                              const float* __restrict__ wd,
                                              unsigned short* __restrict__ wdt,
                                              const float* __restrict__ bfv,
                                              float2* __restrict__ bfi) {
  int blk = blockIdx.x;
  if (blk < 16384) {                       // cast x f32 -> bf16
    size_t i = ((size_t)blk * 256 + threadIdx.x) * 4;
    float4 v = *(const float4*)(x + i);
    *(ushort4*)(xhi + i) = make_ushort4(f2bf(v.x), f2bf(v.y), f2bf(v.z), f2bf(v.w));
    return;
  }
  blk -= 16384;
  if (blk < 4096) {                        // wf [1024][4096] -> wfh interleaved [4096][1024]
    __shared__ float tile[32][33];
    int tx = threadIdx.x & 31, ty = threadIdx.x >> 5;
    int bx = blk & 127, by = blk >> 7;     // 128 x 32
    int c0 = bx * 32, r0 = by * 32;
#pragma unroll
    for (int i = 0; i < 4; ++i)
      tile[ty + 8 * i][tx] = wf[(size_t)(r0 + ty + 8 * i) * 4096 + (c0 + tx)];
    __syncthreads();
#pragma unroll
    for (int i = 0; i < 4; ++i) {
      int j = c0 + ty + 8 * i;             // original wf column
      int r = (j < 2048) ? (2 * j) : (2 * (j - 2048) + 1);
      wfh[(size_t)r * 1024 + (r0 + tx)] = f2bf(tile[tx][ty + 8 * i]);
    }
    return;
  }
  blk -= 4096;
  if (blk < 2048) {                        // wd [2048][1024] -> wdt [1024][2048]
    __shared__ float tile[32][33];
    int tx = threadIdx.x & 31, ty = threadIdx.x >> 5;
    int bx = blk & 31, by = blk >> 5;      // 32 x 64
    int c0 = bx * 32, r0 = by * 32;
#pragma unroll
    for (int i = 0; i < 4; ++i)
      tile[ty + 8 * i][tx] = wd[(size_t)(r0 + ty + 8 * i) * 1024 + (c0 + tx)];
    __syncthreads();
#pragma unroll
    for (int i = 0; i < 4; ++i)
      wdt[(size_t)(c0 + ty + 8 * i) * 2048 + (r0 + tx)] = f2bf(tile[tx][ty + 8 * i]);
    return;
  }
  blk -= 2048;                             // bias pack: bfi[e] = (b_f[e], b_f[2048+e])
  int i = blk * 256 + threadIdx.x;
  if (i < 2048) bfi[i] = make_float2(bfv[i], bfv[2048 + i]);
}

// ---------- GEMM: A[M][K] (bf16, k-contig), B[N][K] (bf16, k-contig) -> C[M][N]
// FINAL (R16 = measured best, 140us GEMM1, MfmaUtil ~43%). Plateau documented:
// ten schedule/shape variants (R6-R17) all land MfmaUtil 41-45%; residual gap
// to the m201 8-phase reference (62%) is fine-grained co-scheduling not
// reproduced in 3 attempts. DO NOT TOUCH.
// 256x256 tile, BK=64, ring-2 (2 x 64KB), distance-1 prefetch, 8 waves
// (2M x 4N, wave-tile 128x64). ONE exact vmcnt(0) + ONE barrier per K-64:
// at the wait, outstanding = only tile u's 8 stage-ops issued one full tile
// (~5000cyc) earlier — exact certification, not a pessimistic drain.
// Race-freedom: stage(u+1) -> buf (u+1)&1 issues after barrier(u); the only
// prior reads of that buffer (tile u-1's) completed before each wave's barrier
// arrival (ds_read -> lgkm-dependent MFMA -> barrier). Read-after-write: the
// top-of-iter vmcnt(0) (own loads) + barrier (collective) certify buf u.
// Per K-tile/wave: 8 stage gloads, 24 ds_read_b128, 64 MFMA in 4 clusters of
// 16 {read a4 | MFMA}, b8 (8 reads) up front.
// LDS swizzle (verified conflict-free family): row of 64 k = 8 slots of 8
// shorts; phys slot p at row r holds global k-chunk p ^ ((r>>1)&7). Stage:
// linear dest, pre-swizzled global chunk (tid&7)^((tid>>4)&7). Read:
// slot = (kh*4+lg) ^ ((r16>>1)&7) -> 2-way banked (free, m136). A and B share
// the lane->k-chunk convention -> contraction correct independent of HW
// k-labeling. C/D layout HW-verified: col = lane&15, row = (lane>>4)*4 + reg.
template<bool BF16OUT>
__global__ __launch_bounds__(512, 2) void k_gemm(const unsigned short* __restrict__ A,
                                                 const unsigned short* __restrict__ B,
                                                 void* __restrict__ Cv, int M, int N, int K) {
  __shared__ unsigned short lds[65536];      // 2 bufs x 32768 shorts = 128 KB
  const int tid = threadIdx.x, wave = tid >> 6, lane = tid & 63;
  const size_t row0 = (size_t)blockIdx.x * 256;
  const size_t col0 = (size_t)blockIdx.y * 256;
  const int wr = wave >> 2, wc = wave & 3;   // 2M x 4N waves, wave-tile 128x64
  const int r16 = lane & 15;
  const int lg = lane >> 4;                  // lane k-group 0..3
  const int xm = (r16 >> 1) & 7;             // row swizzle mask
  const int gchunk = (tid & 7) ^ ((tid >> 4) & 7);   // stage pre-swizzled k-chunk

  f32x4 acc[8][4];
#pragma unroll
  for (int i = 0; i < 8; ++i)
#pragma unroll
    for (int j = 0; j < 4; ++j) acc[i][j] = (f32x4){0.f, 0.f, 0.f, 0.f};

  // stage one 8KB region (arr 0=A,1=B; reg = 64-row slab 0..3) of K-tile kt
  // into ring buffer b. Thread: row reg*64 + (tid>>3), 16B at slot tid&7.
  auto SREG = [&](int b, int arr, int reg, int kt) {
    const unsigned short* src = arr ? B : A;
    size_t grow = (arr ? col0 : row0) + (size_t)(reg * 64 + (tid >> 3));
    gload16(src + grow * (size_t)K + (size_t)(kt * 64 + gchunk * 8),
            &lds[(b << 15) + arr * 16384 + reg * 4096 + wave * 512]);
  };
  auto STAGE = [&](int b, int kt) {
#pragma unroll
    for (int reg = 0; reg < 4; ++reg) SREG(b, 0, reg, kt);
#pragma unroll
    for (int reg = 0; reg < 4; ++reg) SREG(b, 1, reg, kt);
  };

  // fragment offsets (shorts): row*64 + swizzled-slot*8
  auto AOFF = [&](int mb, int kh) -> int {
    int r = wr * 128 + mb * 16 + r16;
    return r * 64 + (((kh * 4 + lg) ^ xm) * 8);
  };
  auto BOFF = [&](int nb, int kh) -> int {
    int r = wc * 64 + nb * 16 + r16;
    return 16384 + r * 64 + (((kh * 4 + lg) ^ xm) * 8);
  };

  STAGE(0, 0);                               // prologue
  const int nT = K >> 6;
  for (int u = 0; u < nT; ++u) {
    const unsigned short* buf = &lds[(u & 1) << 15];
    asm volatile("s_waitcnt vmcnt(0)" ::: "memory");   // exact cert of tile u
    asm volatile("s_barrier" ::: "memory");
    if (u + 1 < nT) STAGE((u & 1) ^ 1, u + 1);         // distance-1 prefetch
    short8 b8[8];
#pragma unroll
    for (int kh = 0; kh < 2; ++kh)
#pragma unroll
      for (int nb = 0; nb < 4; ++nb)
        b8[kh * 4 + nb] = *(const short8*)&buf[BOFF(nb, kh)];
#pragma unroll
    for (int kh = 0; kh < 2; ++kh) {
      short8 a4[4];
#pragma unroll
      for (int mb = 0; mb < 4; ++mb)
        a4[mb] = *(const short8*)&buf[AOFF(mb, kh)];
      __builtin_amdgcn_s_setprio(1);
#pragma unroll
      for (int mb = 0; mb < 4; ++mb)
#pragma unroll
        for (int nb = 0; nb < 4; ++nb)
          acc[mb][nb] = __builtin_amdgcn_mfma_f32_16x16x32_bf16(a4[mb], b8[kh * 4 + nb], acc[mb][nb], 0, 0, 0);
      __builtin_amdgcn_s_setprio(0);
#pragma unroll
      for (int mb = 0; mb < 4; ++mb)
        a4[mb] = *(const short8*)&buf[AOFF(4 + mb, kh)];
      __builtin_amdgcn_s_setprio(1);
#pragma unroll
      for (int mb = 0; mb < 4; ++mb)
#pragma unroll
        for (int nb = 0; nb < 4; ++nb)
          acc[4 + mb][nb] = __builtin_amdgcn_mfma_f32_16x16x32_bf16(a4[mb], b8[kh * 4 + nb], acc[4 + mb][nb], 0, 0, 0);
      __builtin_amdgcn_s_setprio(0);
    }
  }

  // C/D layout (HW-verified): col = lane&15, row = (lane>>4)*4 + reg
#pragma unroll
  for (int m = 0; m < 8; ++m)
#pragma unroll
    for (int n = 0; n < 4; ++n) {
      size_t row = row0 + wr * 128 + m * 16 + (lane >> 4) * 4;
      size_t col = col0 + wc * 64 + n * 16 + r16;
      if (BF16OUT) {
        unsigned short* C = (unsigned short*)Cv;
#pragma unroll
        for (int r = 0; r < 4; ++r) C[(row + r) * (size_t)N + col] = f2bf(acc[m][n][r]);
      } else {
        float* C = (float*)Cv;
#pragma unroll
        for (int r = 0; r < 4; ++r) C[(row + r) * (size_t)N + col] = acc[m][n][r];
      }
    }
}

// ---------- scan constants ----------
#define SB 4
#define ST 4096
#define SE 2048
#define CHUNK 64
#define NCHUNK 64
#define NCHAIN (SB * SE)  // 8192

// LINEAR-SPACE scan: h_t = c*h_{t-1} + v, c = sigmoid(-k), v = sigmoid(k)*g(hx).
// All positive, h in [~1e-7, ~150] — f32-safe. Cancellation-free c.
// proj INTERLEAVED: word e of a row = (k_e lo, hx_e hi).
__device__ __forceinline__ void transform_lin(float k, float hx, float& c, float& v) {
  float e = __expf(-k);
  float r = __builtin_amdgcn_rcpf(1.f + e);    // sigmoid(k)
  c = e * r;                                   // sigmoid(-k), no cancellation
  float e2 = __expf(-hx);
  float sg = __builtin_amdgcn_rcpf(1.f + e2);  // sigmoid(hx)
  float g = (hx >= 0.f) ? (hx + 0.5f) : sg;    // g(hx)
  v = r * g;
}

// K2: transforms + chunk-local linear scan (from 0) -> chunk summaries
__global__ __launch_bounds__(256) void k_scan1(const unsigned int* __restrict__ proj32,
                                               const float2* __restrict__ bfi,
                                               float* __restrict__ Ac,
                                               float* __restrict__ Bc) {
  int idx = blockIdx.x * 256 + threadIdx.x;  // (c, b, e) with e fastest
  int e = idx & (SE - 1), b = (idx >> 11) & 3, c = idx >> 13;
  const float2 bb = bfi[e];
  float A = 1.f, S = 0.f;
  size_t base = ((size_t)(b * ST + c * CHUNK)) * SE + e;
  for (int i = 0; i < CHUNK; ++i) {
    unsigned int w = proj32[base];
    float cc, vv;
    transform_lin(bflo(w) + bb.x, bfhi(w) + bb.y, cc, vv);
    A *= cc;
    S = fmaf(cc, S, vv);
    base += SE;
  }
  int chain = b * SE + e;
  Ac[(size_t)c * NCHAIN + chain] = A;
  Bc[(size_t)c * NCHAIN + chain] = S;
}

// K3: scan over chunk summaries: H_{c+1} = A_c*H_c + B_c; H_0 = exp(lh0)
__global__ __launch_bounds__(256) void k_scan2(const float* __restrict__ lh0,
                                               const float* __restrict__ Ac,
                                               const float* __restrict__ Bc,
                                               float* __restrict__ Hin) {
  int chain = blockIdx.x * 256 + threadIdx.x;  // 8192 = b*E + e
  float H = __expf(lh0[chain]);
  for (int c = 0; c < NCHUNK; ++c) {
    Hin[(size_t)c * NCHAIN + chain] = H;
    H = fmaf(Ac[(size_t)c * NCHAIN + chain], H, Bc[(size_t)c * NCHAIN + chain]);
  }
}

// K4: replay linear scan; emit h_t (bf16) and out2 = log(h) slices
__global__ __launch_bounds__(256) void k_scan3(const unsigned int* __restrict__ proj32,
                                               const float2* __restrict__ bfi,
                                               const float* __restrict__ Hin,
                                               unsigned short* __restrict__ ht,
                                               float* __restrict__ out2) {
  int idx = blockIdx.x * 256 + threadIdx.x;
  int e = idx & (SE - 1), b = (idx >> 11) & 3, c = idx >> 13;
  const float2 bb = bfi[e];
  float S = Hin[(size_t)c * NCHAIN + b * SE + e];
  size_t base = ((size_t)(b * ST + c * CHUNK)) * SE + e;
  int t = c * CHUNK;
  size_t hto = ((size_t)(b * ST + t)) * SE + e;
  for (int i = 0; i < CHUNK; ++i, ++t) {
    unsigned int w = proj32[base];
    float cc, vv;
    transform_lin(bflo(w) + bb.x, bfhi(w) + bb.y, cc, vv);
    S = fmaf(cc, S, vv);
    ht[hto] = f2bf(S);
    if (t >= 2 && ((t - 2) % 3) == 0) {   // t in {2,5,...,4094}
      int j = (t - 2) / 3;
      out2[((size_t)b * 1365 + j) * SE + e] = __logf(S);
    }
    base += SE;
    hto += SE;
  }
}

// ---------- launch ----------
extern "C" void kernel_launch(void* const* d_in, const int* in_sizes, int n_in,
                              void* d_out, int out_size, void* d_ws, size_t ws_size,
                              hipStream_t stream) {
  const float* x   = (const float*)d_in[0];
  const float* lh0 = (const float*)d_in[1];
  const float* wf  = (const float*)d_in[2];
  const float* bfv = (const float*)d_in[3];
  const float* wd  = (const float*)d_in[4];
  float* out1 = (float*)d_out;
  float* out2 = out1 + (size_t)SB * ST * 1024;

  char* p = (char*)d_ws;
  unsigned short* proj = (unsigned short*)p; p += 16384ull * 4096 * 2;  // 134 MB bf16
  unsigned short* xhi  = (unsigned short*)p; p += 16384ull * 1024 * 2;
  unsigned short* wfh  = (unsigned short*)p; p += 4096ull * 1024 * 2;
  unsigned short* wdt  = (unsigned short*)p; p += 1024ull * 2048 * 2;
  unsigned short* ht   = (unsigned short*)p; p += 16384ull * 2048 * 2;  // 67 MB
  float* Ac            = (float*)p;          p += 64ull * 8192 * 4;
  float* Bc            = (float*)p;          p += 64ull * 8192 * 4;
  float* Hin           = (float*)p;          p += 64ull * 8192 * 4;
  float2* bfi          = (float2*)p;         p += 2048ull * 8;

  // merged pre-pass
  hipLaunchKernelGGL(k_prep, dim3(16384 + 4096 + 2048 + 8), dim3(256), 0, stream,
                     x, xhi, wf, wfh, wd, wdt, bfv, bfi);
  // GEMM1 (bf16 in/out): proj = x @ w_f (cols interleaved via wfh row perm)
  hipLaunchKernelGGL((k_gemm<true>), dim3(64, 16), dim3(512), 0, stream,
                     xhi, wfh, (void*)proj, 16384, 4096, 1024);
  // 3-pass chunked LINEAR-space scan (proj read-only, word-coalesced)
  hipLaunchKernelGGL(k_scan1, dim3(2048), dim3(256), 0, stream,
                     (const unsigned int*)proj, bfi, Ac, Bc);
  hipLaunchKernelGGL(k_scan2, dim3(32), dim3(256), 0, stream, lh0, Ac, Bc, Hin);
  hipLaunchKernelGGL(k_scan3, dim3(2048), dim3(256), 0, stream,
                     (const unsigned int*)proj, bfi, Hin, ht, out2);
  // GEMM2 (bf16 in, f32 out): out1 = h_t @ w_down
  hipLaunchKernelGGL((k_gemm<false>), dim3(64, 4), dim3(512), 0, stream,
                     ht, wdt, (void*)out1, 16384, 1024, 2048);
}